// Round 7
// baseline (256.526 us; speedup 1.0000x reference)
//
#include <hip/hip_runtime.h>
#include <hip/hip_bf16.h>
#include <cstddef>

// Problem constants (SelfAttention: B=4, T=2048, H=16, Dh=64, C=1024)
#define B_  4
#define T_  2048
#define H_  16
#define DH  64
#define C_  1024
#define BH  64    // B_*H_

typedef float  f32x16 __attribute__((ext_vector_type(16)));
typedef __bf16 bf16x8 __attribute__((ext_vector_type(8)));
typedef unsigned int u32;
typedef const __attribute__((address_space(1))) u32* gas_u32p;
typedef __attribute__((address_space(3))) u32* las_u32p;

#define MFMA32(a, b, c) __builtin_amdgcn_mfma_f32_32x32x16_bf16(a, b, c, 0, 0, 0)

// mfma_f32_32x32x16_bf16 layouts (m74/m101 verified):
//   A[m][k]: m = lane&31, k = (lane>>5)*8 + j
//   B[k][n]: n = lane&31, k = (lane>>5)*8 + j
//   C/D:     col = lane&31, row = (reg&3) + 8*(reg>>2) + 4*(lane>>5)
//
// HW lessons (this session):
//   R3/R5: uint4 prefetch held across MFMA => scratch spill (+250MB WRITE).
//   R4: frag reads at 2-row stride-72 => 8-way conflicts.
//   R6: XOR-chunk DMA tiles => 8.4M conflicts + VALU addressing overhead.
//   Stride-72 padded tiles + immediate ds_write staging (R2): 0 conflicts,
//   VGPR 64. R2 was LDS-pipe-bound (~82%) => this round removes the P
//   round-trip via operand-swapped S^T + shfl_xor(32) lane-pair exchange.

__device__ __forceinline__ unsigned pack2(float a, float b) {
    return ((unsigned)__builtin_bit_cast(unsigned short, (__bf16)b) << 16)
         | (unsigned)__builtin_bit_cast(unsigned short, (__bf16)a);
}

// (kept for proj_kernel) DMA-stage 8 rows of a row-major tile, XOR layout.
__device__ __forceinline__ void dma8(const __bf16* gbase, size_t rowstride,
                                     __bf16* lds_rowbase, int r8, int lane)
{
    const int r = r8 + (lane >> 3);
    const int j = (lane & 7) ^ (r & 7);
    const __bf16* src = gbase + (size_t)r * rowstride + j * 8;
    __builtin_amdgcn_global_load_lds((gas_u32p)src, (las_u32p)lds_rowbase,
                                     16, 0, 0);
}
__device__ __forceinline__ bf16x8 frag(const __bf16* tile, int row, int chunk)
{
    return *(const bf16x8*)&tile[row * 64 + (((chunk ^ (row & 7))) << 3)];
}

// ---------------------------------------------------------------------------
// Kernel 1: QKV projection (R2-proven) + one-time Wp fp32->bf16 conversion.
// q gets (1/sqrt(1024))*log2(e) folded (attention uses exp2). q,k written
// [bh][t][d]; v transposed through LDS to vt[bh][d][t].
// ---------------------------------------------------------------------------
__global__ __launch_bounds__(256) void qkv_kernel(
    const float* __restrict__ x,
    const float* __restrict__ Wq, const float* __restrict__ bq,
    const float* __restrict__ Wk, const float* __restrict__ bk,
    const float* __restrict__ Wv, const float* __restrict__ bv,
    const float* __restrict__ Wp, __bf16* __restrict__ Wp16,
    __bf16* __restrict__ q, __bf16* __restrict__ k, __bf16* __restrict__ vt)
{
    __shared__ __bf16 Xs[128 * 72];
    __shared__ __bf16 Ws[3][64 * 72];
    __bf16* Vtl = Xs;   // alias after xf hoist: V^T [e][t_local], stride 136

    const int tt  = blockIdx.x;
    const int bh  = blockIdx.y;
    const int b   = bh >> 4, h = bh & 15;
    const int t0  = tt * 128;
    const int tid = threadIdx.x;
    const int wave = tid >> 6, lane = tid & 63;
    const int m = lane & 31, hh = lane >> 5;

    {   // one-time Wp conversion
        const int flat = (bh * 16 + tt) * 256 + tid;
        const float4 w4 = *(const float4*)(Wp + (size_t)flat * 4);
        uint2 pk; pk.x = pack2(w4.x, w4.y); pk.y = pack2(w4.z, w4.w);
        *(uint2*)(Wp16 + (size_t)flat * 4) = pk;
    }

    #pragma unroll
    for (int i = 0; i < 8; ++i) {
        const int idx = i * 256 + tid;
        const int r = idx >> 4, c = (idx & 15) * 4;
        const float4 x4 = *(const float4*)(x + ((size_t)(b * T_ + t0 + r)) * C_ + h * DH + c);
        *(unsigned*)&Xs[r * 72 + c]     = pack2(x4.x, x4.y);
        *(unsigned*)&Xs[r * 72 + c + 2] = pack2(x4.z, x4.w);
    }
    #pragma unroll
    for (int i = 0; i < 4; ++i) {
        const int idx = i * 256 + tid;
        const int r = idx >> 4, c = (idx & 15) * 4;
        const float* wsrc[3] = {Wq, Wk, Wv};
        #pragma unroll
        for (int wv_ = 0; wv_ < 3; ++wv_) {
            const float4 w4 = *(const float4*)(wsrc[wv_] + r * 64 + c);
            *(unsigned*)&Ws[wv_][r * 72 + c]     = pack2(w4.x, w4.y);
            *(unsigned*)&Ws[wv_][r * 72 + c + 2] = pack2(w4.z, w4.w);
        }
    }
    __syncthreads();

    bf16x8 xf[4];
    #pragma unroll
    for (int ks = 0; ks < 4; ++ks)
        xf[ks] = *(const bf16x8*)&Xs[(wave * 32 + m) * 72 + ks * 16 + hh * 8];
    __syncthreads();

    const float sQ = 0.03125f * 1.44269504f;

    #pragma unroll
    for (int mat = 0; mat < 3; ++mat) {
        f32x16 acc0 = {}, acc1 = {};
        #pragma unroll
        for (int ks = 0; ks < 4; ++ks) {
            const bf16x8 w0 = *(const bf16x8*)&Ws[mat][(m) * 72 + ks * 16 + hh * 8];
            const bf16x8 w1 = *(const bf16x8*)&Ws[mat][(32 + m) * 72 + ks * 16 + hh * 8];
            acc0 = MFMA32(xf[ks], w0, acc0);
            acc1 = MFMA32(xf[ks], w1, acc1);
        }
        const float* bias = (mat == 0) ? bq : (mat == 1) ? bk : bv;
        const float b0 = bias[m], b1 = bias[32 + m];
        #pragma unroll
        for (int r = 0; r < 16; ++r) {
            const int R = (r & 3) + 8 * (r >> 2) + 4 * hh;
            const int tloc = wave * 32 + R;
            const float v0 = acc0[r] + b0, v1 = acc1[r] + b1;
            if (mat == 0) {
                const size_t base = ((size_t)bh * T_ + t0 + tloc) * DH;
                q[base + m]      = (__bf16)(v0 * sQ);
                q[base + 32 + m] = (__bf16)(v1 * sQ);
            } else if (mat == 1) {
                const size_t base = ((size_t)bh * T_ + t0 + tloc) * DH;
                k[base + m]      = (__bf16)v0;
                k[base + 32 + m] = (__bf16)v1;
            } else {
                Vtl[(m) * 136 + tloc]      = (__bf16)v0;
                Vtl[(32 + m) * 136 + tloc] = (__bf16)v1;
            }
        }
    }
    __syncthreads();
    #pragma unroll
    for (int i = 0; i < 4; ++i) {
        const int idx = i * 256 + tid;
        const int e = idx >> 4, c = (idx & 15) * 8;
        *(uint4*)(vt + ((size_t)(bh * 64 + e)) * T_ + t0 + c) = *(uint4*)&Vtl[e * 136 + c];
    }
}

// ---------------------------------------------------------------------------
// Kernel 2: flash attention, S^T formulation — no P LDS round-trip.
//   S^T = MFMA(A=K rows, B=Q frag): lane holds P for q=lane&31, keys split
//   between lane m (h=0) and lane m+32 (h=1). P A-frags for O=P*V assembled
//   by shfl_xor(32) pair exchange + cndmask (verified index map in comments).
// K/V staged to stride-72 LDS (R2 pattern, 0 conflicts). Q frags direct from
// global (no LDS). lsum is a per-lane scalar; redistributed once via 512B LDS.
// LDS = 18.9 KB.
// ---------------------------------------------------------------------------
__global__ __launch_bounds__(256, 3) void attn_kernel(
    const __bf16* __restrict__ q, const __bf16* __restrict__ k,
    const __bf16* __restrict__ vt, __bf16* __restrict__ o)
{
    __shared__ __bf16 Ks[64 * 72];      // K tile [k_row][d]
    __shared__ __bf16 Vts[64 * 72];     // V^T tile [d][k_row]
    __shared__ float  Ls[128];          // 1/l per q-row (epilogue only)

    const int bh  = blockIdx.y;
    const int q0  = blockIdx.x * 128;
    const int tid = threadIdx.x;
    const int wave = tid >> 6, lane = tid & 63;
    const int m = lane & 31, h = lane >> 5;
    const int qrow0 = wave * 32;

    const __bf16* qb = q  + (size_t)bh * T_ * DH;
    const __bf16* kb = k  + (size_t)bh * T_ * DH;
    const __bf16* vb = vt + (size_t)bh * DH * T_;

    // Q fragments straight from global: lane m <-> q-row qrow0+m (B operand)
    bf16x8 qf[4];
    #pragma unroll
    for (int ks = 0; ks < 4; ++ks)
        qf[ks] = *(const bf16x8*)(qb + (size_t)(q0 + qrow0 + m) * DH + ks * 16 + h * 8);

    f32x16 O0 = {}, O1 = {};
    float lsum = 0.f;

    for (int kt = 0; kt < T_; kt += 64) {
        __syncthreads();   // prior iteration's Ks/Vts reads complete
        #pragma unroll
        for (int i = 0; i < 2; ++i) {
            const int idx = i * 256 + tid;
            const int r = idx >> 3, c = (idx & 7) * 8;
            *(uint4*)&Ks[r * 72 + c]  = *(const uint4*)(kb + (size_t)(kt + r) * DH + c);
            *(uint4*)&Vts[r * 72 + c] = *(const uint4*)(vb + (size_t)r * T_ + kt + c);
        }
        __syncthreads();

        // S^T tiles: St0 = keys 0..31 (A = K rows m), St1 = keys 32..63.
        // C-layout: col = q = lane&31, row = key = (reg&3)+8*(reg>>2)+4h.
        f32x16 St0 = {}, St1 = {};
        #pragma unroll
        for (int ks = 0; ks < 4; ++ks) {
            const bf16x8 k0 = *(const bf16x8*)&Ks[(m) * 72 + ks * 16 + h * 8];
            const bf16x8 k1 = *(const bf16x8*)&Ks[(32 + m) * 72 + ks * 16 + h * 8];
            St0 = MFMA32(k0, qf[ks], St0);
            St1 = MFMA32(k1, qf[ks], St1);
        }

        // P = exp2(S^T); pack pairs (regs 2i,2i+1 = consecutive keys)
        u32 pk0[8], pk1[8];
        #pragma unroll
        for (int i = 0; i < 8; ++i) {
            const float a0 = exp2f(St0[2 * i]), a1 = exp2f(St0[2 * i + 1]);
            const float b0 = exp2f(St1[2 * i]), b1 = exp2f(St1[2 * i + 1]);
            lsum += a0 + a1 + b0 + b1;
            pk0[i] = pack2(a0, a1);
            pk1[i] = pack2(b0, b1);
        }

        // O += P V. A-frag(ks=2*tau+G), keys 16ks+8h..+7:
        //   h=0: {own pk[4G], own pk[4G+1], partner pk[4G], partner pk[4G+1]}
        //   h=1: {partner pk[4G+2..3], own pk[4G+2..3]}
        // Exchange: send = h ? pk[4G+t] : pk[4G+2+t]; recv via shfl_xor(32).
        #pragma unroll
        for (int ks = 0; ks < 4; ++ks) {
            const u32* pk = (ks < 2) ? pk0 : pk1;
            const int G4 = (ks & 1) * 4;
            const u32 s0 = h ? pk[G4]     : pk[G4 + 2];
            const u32 s1 = h ? pk[G4 + 1] : pk[G4 + 3];
            const u32 r0 = (u32)__shfl_xor((int)s0, 32);
            const u32 r1 = (u32)__shfl_xor((int)s1, 32);
            uint4 w;
            w.x = h ? r0         : pk[G4];
            w.y = h ? r1         : pk[G4 + 1];
            w.z = h ? pk[G4 + 2] : r0;
            w.w = h ? pk[G4 + 3] : r1;
            const bf16x8 pf = __builtin_bit_cast(bf16x8, w);
            const bf16x8 v0 = *(const bf16x8*)&Vts[(m) * 72 + ks * 16 + h * 8];
            const bf16x8 v1 = *(const bf16x8*)&Vts[(32 + m) * 72 + ks * 16 + h * 8];
            O0 = MFMA32(pf, v0, O0);
            O1 = MFMA32(pf, v1, O1);
        }
    }

    // per-q 1/l: lane m + lane m+32 hold complementary key halves for q=m
    const float tot = lsum + __shfl_xor(lsum, 32);
    if (h == 0) Ls[qrow0 + m] = 1.0f / tot;   // same-wave readers below

    __bf16* ob = o + (size_t)bh * T_ * DH;
    #pragma unroll
    for (int r = 0; r < 16; ++r) {
        const int R = (r & 3) + 8 * (r >> 2) + 4 * h;
        const float inv = Ls[qrow0 + R];      // 2 addrs/wave -> broadcast
        const size_t row = (size_t)(q0 + qrow0 + R) * DH;
        ob[row + m]      = (__bf16)(O0[r] * inv);
        ob[row + 32 + m] = (__bf16)(O1[r] * inv);
    }
}

// ---------------------------------------------------------------------------
// Kernel 3: output projection (R6 config — best measured non-attn): 128x128
// bf16 GEMM, DMA double-buffered, XOR tiles. 64 KB LDS -> 2 blocks/CU.
// ---------------------------------------------------------------------------
__global__ __launch_bounds__(256, 2) void proj_kernel(
    const __bf16* __restrict__ a,      // [bh][t][d]
    const __bf16* __restrict__ Wp16, const float* __restrict__ bp,
    float* __restrict__ out)
{
    __shared__ __bf16 As[2][128 * 64];
    __shared__ __bf16 Bs[2][128 * 64];

    const int tb = blockIdx.x, eb = blockIdx.y;
    const int tid = threadIdx.x;
    const int wave = tid >> 6, lane = tid & 63;
    const int m = lane & 31, h = lane >> 5;
    const int tok0 = tb * 128;
    const int b = tok0 >> 11, t0 = tok0 & (T_ - 1);
    const int e0 = eb * 128;

    #pragma unroll
    for (int s = 0; s < 4; ++s) {
        const int r8 = wave * 32 + s * 8;
        dma8(a + ((size_t)(b * H_) * T_ + t0) * DH, DH, &As[0][r8 * 64], r8, lane);
        dma8(Wp16 + (size_t)e0 * C_, C_, &Bs[0][r8 * 64], r8, lane);
    }
    __syncthreads();

    f32x16 acc[4] = {f32x16{}, f32x16{}, f32x16{}, f32x16{}};

    #pragma unroll 2
    for (int cb = 0; cb < 16; ++cb) {
        const int cur = cb & 1;
        if (cb < 15) {
            #pragma unroll
            for (int s = 0; s < 4; ++s) {
                const int r8 = wave * 32 + s * 8;
                dma8(a + ((size_t)(b * H_ + cb + 1) * T_ + t0) * DH, DH,
                     &As[cur ^ 1][r8 * 64], r8, lane);
                dma8(Wp16 + (size_t)e0 * C_ + (cb + 1) * 64, C_,
                     &Bs[cur ^ 1][r8 * 64], r8, lane);
            }
        }

        #pragma unroll
        for (int ks = 0; ks < 4; ++ks) {
            const bf16x8 af = frag(As[cur], wave * 32 + m, ks * 2 + h);
            #pragma unroll
            for (int n = 0; n < 4; ++n) {
                const bf16x8 bf = frag(Bs[cur], n * 32 + m, ks * 2 + h);
                acc[n] = MFMA32(af, bf, acc[n]);
            }
        }
        __syncthreads();
    }

    #pragma unroll
    for (int n = 0; n < 4; ++n) {
        const int e = e0 + n * 32 + m;
        const float bias = bp[e];
        #pragma unroll
        for (int r = 0; r < 16; ++r) {
            const int R = (r & 3) + 8 * (r >> 2) + 4 * h;
            out[(size_t)(tok0 + wave * 32 + R) * C_ + e] = acc[n][r] + bias;
        }
    }
}

// ---------------------------------------------------------------------------
// Workspace (bf16): q | k | vt | attn_out (16MB each) | Wp16 (2MB) = 69MB.
// ---------------------------------------------------------------------------
extern "C" void kernel_launch(void* const* d_in, const int* in_sizes, int n_in,
                              void* d_out, int out_size, void* d_ws, size_t ws_size,
                              hipStream_t stream)
{
    const float* x  = (const float*)d_in[0];
    const float* Wq = (const float*)d_in[1];
    const float* bq = (const float*)d_in[2];
    const float* Wk = (const float*)d_in[3];
    const float* bk = (const float*)d_in[4];
    const float* Wv = (const float*)d_in[5];
    const float* bv = (const float*)d_in[6];
    const float* Wp = (const float*)d_in[7];
    const float* bp = (const float*)d_in[8];

    const size_t N = (size_t)BH * T_ * DH;
    __bf16* qws  = (__bf16*)d_ws;
    __bf16* kws  = qws + N;
    __bf16* vtws = kws + N;
    __bf16* ows  = vtws + N;
    __bf16* wp16 = ows + N;

    qkv_kernel<<<dim3(16, 64), 256, 0, stream>>>(
        x, Wq, bq, Wk, bk, Wv, bv, Wp, wp16, qws, kws, vtws);
    attn_kernel<<<dim3(16, 64), 256, 0, stream>>>(qws, kws, vtws, ows);
    proj_kernel<<<dim3(64, 8), 256, 0, stream>>>(ows, wp16, bp, (float*)d_out);
}